// Round 1
// baseline (30.561 us; speedup 1.0000x reference)
//
#include <hip/hip_runtime.h>
#include <cmath>

// RMSDLoss (batched Kabsch superimposer RMSD, mean over batch).
// Single pass: per-batch sufficient statistics -> 3x3 covariance -> SVD
// singular values via analytic symmetric eigen-solve of A^T A (fp64, thread 0
// only) -> rms = sqrt((E0 - 2*(s0+s1+sign(det)*s2))/N). Then mean over B.

constexpr int BLOCK = 256;
constexpr int NWAVE = BLOCK / 64;

__global__ __launch_bounds__(BLOCK) void rmsd_per_batch(
    const float* __restrict__ yp,   // [B,N,3] coords (y_prime)
    const float* __restrict__ yr,   // [B,N,3] reference (y)
    float* __restrict__ rms_out,    // [B]
    int n)                          // atoms per row
{
    const int b   = blockIdx.x;
    const int tid = threadIdx.x;
    const size_t row = (size_t)b * (size_t)n * 3u;
    const float4* p4 = (const float4*)(yp + row);
    const float4* r4 = (const float4*)(yr + row);

    // 17 partial sums (fp32): means(6), sumsq(2), cross 3x3 (9)
    float s1x=0.f,s1y=0.f,s1z=0.f, s2x=0.f,s2y=0.f,s2z=0.f, sq1=0.f,sq2=0.f;
    float c00=0.f,c01=0.f,c02=0.f,c10=0.f,c11=0.f,c12=0.f,c20=0.f,c21=0.f,c22=0.f;

    const int ngroups = n >> 2;   // 4 atoms = 12 floats = 3 float4 per group
    for (int g = tid; g < ngroups; g += BLOCK) {
        float4 a0 = p4[g*3+0], a1 = p4[g*3+1], a2 = p4[g*3+2];
        float4 b0 = r4[g*3+0], b1 = r4[g*3+1], b2 = r4[g*3+2];
        float px[4]={a0.x,a0.w,a1.z,a2.y};
        float py[4]={a0.y,a1.x,a1.w,a2.z};
        float pz[4]={a0.z,a1.y,a2.x,a2.w};
        float qx[4]={b0.x,b0.w,b1.z,b2.y};
        float qy[4]={b0.y,b1.x,b1.w,b2.z};
        float qz[4]={b0.z,b1.y,b2.x,b2.w};
        #pragma unroll
        for (int k=0;k<4;k++){
            s1x+=px[k]; s1y+=py[k]; s1z+=pz[k];
            s2x+=qx[k]; s2y+=qy[k]; s2z+=qz[k];
            sq1 = fmaf(px[k],px[k], fmaf(py[k],py[k], fmaf(pz[k],pz[k], sq1)));
            sq2 = fmaf(qx[k],qx[k], fmaf(qy[k],qy[k], fmaf(qz[k],qz[k], sq2)));
            c00=fmaf(px[k],qx[k],c00); c01=fmaf(px[k],qy[k],c01); c02=fmaf(px[k],qz[k],c02);
            c10=fmaf(py[k],qx[k],c10); c11=fmaf(py[k],qy[k],c11); c12=fmaf(py[k],qz[k],c12);
            c20=fmaf(pz[k],qx[k],c20); c21=fmaf(pz[k],qy[k],c21); c22=fmaf(pz[k],qz[k],c22);
        }
    }

    float vals[17] = {s1x,s1y,s1z,s2x,s2y,s2z,sq1,sq2,
                      c00,c01,c02,c10,c11,c12,c20,c21,c22};
    __shared__ float sred[NWAVE][17];
    const int wave = tid >> 6, lane = tid & 63;
    #pragma unroll
    for (int i=0;i<17;i++){
        float v = vals[i];
        #pragma unroll
        for (int off=32; off>0; off>>=1) v += __shfl_down(v, off, 64);
        if (lane==0) sred[wave][i] = v;
    }
    __syncthreads();

    if (tid == 0) {
        double t[17];
        #pragma unroll
        for (int i=0;i<17;i++){
            double s = 0.0;
            #pragma unroll
            for (int w=0;w<NWAVE;w++) s += (double)sred[w][i];
            t[i] = s;
        }
        const double dn = (double)n;
        const double m1[3] = {t[0]/dn, t[1]/dn, t[2]/dn};
        const double m2[3] = {t[3]/dn, t[4]/dn, t[5]/dn};
        const double E0 =
            (t[6] - dn*(m1[0]*m1[0]+m1[1]*m1[1]+m1[2]*m1[2])) +
            (t[7] - dn*(m2[0]*m2[0]+m2[1]*m2[1]+m2[2]*m2[2]));
        // A[i][j] = sum c_i r_j = cross_ij - n*m1_i*m2_j
        double A[3][3];
        A[0][0]=t[8] -dn*m1[0]*m2[0]; A[0][1]=t[9] -dn*m1[0]*m2[1]; A[0][2]=t[10]-dn*m1[0]*m2[2];
        A[1][0]=t[11]-dn*m1[1]*m2[0]; A[1][1]=t[12]-dn*m1[1]*m2[1]; A[1][2]=t[13]-dn*m1[1]*m2[2];
        A[2][0]=t[14]-dn*m1[2]*m2[0]; A[2][1]=t[15]-dn*m1[2]*m2[1]; A[2][2]=t[16]-dn*m1[2]*m2[2];

        const double det =
              A[0][0]*(A[1][1]*A[2][2]-A[1][2]*A[2][1])
            - A[0][1]*(A[1][0]*A[2][2]-A[1][2]*A[2][0])
            + A[0][2]*(A[1][0]*A[2][1]-A[1][1]*A[2][0]);

        // B = A^T A (symmetric PSD); eigenvalues analytically
        double B00=0,B01=0,B02=0,B11=0,B12=0,B22=0;
        #pragma unroll
        for (int k=0;k<3;k++){
            B00 += A[k][0]*A[k][0]; B01 += A[k][0]*A[k][1]; B02 += A[k][0]*A[k][2];
            B11 += A[k][1]*A[k][1]; B12 += A[k][1]*A[k][2]; B22 += A[k][2]*A[k][2];
        }
        const double q  = (B00+B11+B22)/3.0;
        const double p1 = B01*B01 + B02*B02 + B12*B12;
        const double p2 = (B00-q)*(B00-q)+(B11-q)*(B11-q)+(B22-q)*(B22-q) + 2.0*p1;
        const double p  = sqrt(p2/6.0);
        double e1, e2, e3;
        if (p < 1e-300) {
            e1 = e2 = e3 = q;
        } else {
            const double C00=(B00-q)/p, C01=B01/p, C02=B02/p;
            const double C11=(B11-q)/p, C12=B12/p, C22=(B22-q)/p;
            double detC = C00*(C11*C22-C12*C12)
                        - C01*(C01*C22-C12*C02)
                        + C02*(C01*C12-C11*C02);
            double rr = detC * 0.5;
            rr = fmin(1.0, fmax(-1.0, rr));
            const double phi = acos(rr)/3.0;
            e1 = q + 2.0*p*cos(phi);
            e3 = q + 2.0*p*cos(phi + 2.0943951023931953);  // +2*pi/3
            e2 = 3.0*q - e1 - e3;
        }
        const double s0 = sqrt(fmax(e1,0.0));
        const double s1 = sqrt(fmax(e2,0.0));
        const double s2 = sqrt(fmax(e3,0.0));
        const double dsign = (det >= 0.0) ? 1.0 : -1.0;
        const double trs = s0 + s1 + dsign*s2;
        const double msd = fmax(0.0, (E0 - 2.0*trs)/dn);
        rms_out[b] = (float)sqrt(msd);
    }
}

__global__ __launch_bounds__(BLOCK) void mean_kernel(
    const float* __restrict__ rms, float* __restrict__ out, int B)
{
    const int tid = threadIdx.x;
    float s = 0.f;
    for (int i = tid; i < B; i += BLOCK) s += rms[i];
    #pragma unroll
    for (int off=32; off>0; off>>=1) s += __shfl_down(s, off, 64);
    __shared__ float sred[NWAVE];
    const int wave = tid >> 6, lane = tid & 63;
    if (lane==0) sred[wave] = s;
    __syncthreads();
    if (tid == 0) {
        float tot = 0.f;
        #pragma unroll
        for (int w=0; w<NWAVE; w++) tot += sred[w];
        out[0] = tot / (float)B;
    }
}

extern "C" void kernel_launch(void* const* d_in, const int* in_sizes, int n_in,
                              void* d_out, int out_size, void* d_ws, size_t ws_size,
                              hipStream_t stream) {
    const float* yp = (const float*)d_in[0];   // y_prime [B,N,3] f32
    const float* yr = (const float*)d_in[1];   // y       [B,N,3] f32
    const int N = 2048;
    const int B = in_sizes[0] / (N * 3);
    float* rms_ws = (float*)d_ws;              // B floats of scratch

    rmsd_per_batch<<<B, BLOCK, 0, stream>>>(yp, yr, rms_ws, N);
    mean_kernel<<<1, BLOCK, 0, stream>>>(rms_ws, (float*)d_out, B);
}